// Round 1
// baseline (339.221 us; speedup 1.0000x reference)
//
#include <hip/hip_runtime.h>

// CutOut fused copy+mask: images (64,512,512,3) f32 -> out, zeroing a
// 50x50 box (clipped) per batch centered at (center_h[b], center_w[b]).
// Output tail: labels (64) as f32.
//
// Memory-bound: 201 MB read + 201 MB write.
// Structure: grid (192, 64) x 256 threads. blockIdx.y = batch index ->
// center loads are wave-uniform scalar loads. Each block owns 1024
// consecutive float4s (4096 elems = ~2.67 rows) of ONE image; a
// block-uniform row-range test sends ~90% of blocks down a pure-copy
// path with 4-deep ILP and nontemporal stores.

#define HALF   25
#define BATCH  64
#define IMG_H  512
#define IMG_W  512
#define IMG_C  3
#define ELEM_PER_IMG (IMG_H * IMG_W * IMG_C)            // 786432
#define VEC_PER_IMG  (ELEM_PER_IMG / 4)                 // 196608
#define VEC_PER_BLOCK 1024
#define BLOCKS_PER_IMG (VEC_PER_IMG / VEC_PER_BLOCK)    // 192 (exact)
#define N_ELEM ((size_t)BATCH * ELEM_PER_IMG)           // 50,331,648

typedef float f4 __attribute__((ext_vector_type(4)));

__global__ __launch_bounds__(256) void cutout_fused(
    const f4* __restrict__ in,
    f4* __restrict__ out,
    const int* __restrict__ center_h,
    const int* __restrict__ center_w,
    const int* __restrict__ labels,
    float* __restrict__ out_labels)
{
    const int b = blockIdx.y;                   // batch index: block-uniform
    const int chb = center_h[b];                // -> s_load (uniform)
    const int cwb = center_w[b];

    if (blockIdx.x == 0 && b == 0 && threadIdx.x < BATCH) {
        out_labels[threadIdx.x] = (float)labels[threadIdx.x];
    }

    const unsigned vbase_img = blockIdx.x * (unsigned)VEC_PER_BLOCK;  // vec idx within image
    const unsigned gvbase    = (unsigned)b * VEC_PER_IMG + vbase_img;
    const f4* __restrict__ src = in  + gvbase + threadIdx.x;
    f4*       __restrict__ dst = out + gvbase + threadIdx.x;

    // Row range covered by this block (elements [e0, e0+4096) of the image).
    const unsigned e0 = vbase_img * 4u;
    const int r0 = (int)((e0 / 3u) >> 9);
    const int r1 = (int)(((e0 + 4095u) / 3u) >> 9);
    const bool overlap = (r1 >= chb - HALF) & (r0 < chb + HALF);

    if (!overlap) {
        // Pure copy: 4 independent 16B loads, then 4 nt stores.
        f4 v0 = src[0];
        f4 v1 = src[256];
        f4 v2 = src[512];
        f4 v3 = src[768];
        __builtin_nontemporal_store(v0, dst);
        __builtin_nontemporal_store(v1, dst + 256);
        __builtin_nontemporal_store(v2, dst + 512);
        __builtin_nontemporal_store(v3, dst + 768);
        return;
    }

    // Mask path (~10% of blocks): per-element box test.
    f4 v0 = src[0];
    f4 v1 = src[256];
    f4 v2 = src[512];
    f4 v3 = src[768];
    f4 vv[4] = {v0, v1, v2, v3};

    #pragma unroll
    for (int k = 0; k < 4; ++k) {
        const unsigned vimg = vbase_img + threadIdx.x + (unsigned)k * 256u; // vec idx in image
        const unsigned idx4 = vimg * 4u;          // elem idx in image, < 786432
        const unsigned pi   = idx4 / 3u;          // pixel of elem 0 (magic-mul)
        const unsigned rem  = idx4 - pi * 3u;     // channel of elem 0

        // pixel p -> (h, w) within this image
        const unsigned p0 = pi;
        const unsigned p1 = pi + 1u;              // always < 262144 for valid vecs
        const int w0 = (int)(p0 & (IMG_W - 1));
        const int h0 = (int)(p0 >> 9);
        const int w1 = (int)(p1 & (IMG_W - 1));
        const int h1 = (int)(p1 >> 9);

        const bool m0 = (h0 >= chb - HALF) & (h0 < chb + HALF) &
                        (w0 >= cwb - HALF) & (w0 < cwb + HALF);
        const bool m1 = (h1 >= chb - HALF) & (h1 < chb + HALF) &
                        (w1 >= cwb - HALF) & (w1 < cwb + HALF);

        // e0 -> p0; e1 -> (rem>=2 ? p1 : p0); e2 -> (rem>=1 ? p1 : p0); e3 -> p1
        const bool me0 = m0;
        const bool me1 = (rem >= 2) ? m1 : m0;
        const bool me2 = (rem >= 1) ? m1 : m0;
        const bool me3 = m1;

        f4 v = vv[k];
        if (me0) v[0] = 0.0f;
        if (me1) v[1] = 0.0f;
        if (me2) v[2] = 0.0f;
        if (me3) v[3] = 0.0f;
        __builtin_nontemporal_store(v, dst + k * 256);
    }
}

extern "C" void kernel_launch(void* const* d_in, const int* in_sizes, int n_in,
                              void* d_out, int out_size, void* d_ws, size_t ws_size,
                              hipStream_t stream) {
    const float* images   = (const float*)d_in[0];
    const int*   labels   = (const int*)  d_in[1];
    const int*   center_h = (const int*)  d_in[2];
    const int*   center_w = (const int*)  d_in[3];
    float* out = (float*)d_out;

    dim3 grid(BLOCKS_PER_IMG, BATCH);            // (192, 64) = 12288 blocks
    cutout_fused<<<grid, 256, 0, stream>>>(
        (const f4*)images, (f4*)out,
        center_h, center_w, labels, out + N_ELEM);
}

// Round 2
// 330.765 us; speedup vs baseline: 1.0256x; 1.0256x over previous
//
#include <hip/hip_runtime.h>

// CutOut fused copy+mask: images (64,512,512,3) f32 -> out, zeroing a
// 50x50 box (clipped) per batch centered at (center_h[b], center_w[b]).
// Output tail: labels (64) as f32.
//
// Memory-bound: 201 MB read + 201 MB write.
// Structure: grid (192, 64) x 256 threads. blockIdx.y = batch index ->
// center loads are block-uniform scalar loads. Each block owns 1024
// consecutive float4s (4096 elems = ~2.67 rows) of ONE image; a
// block-uniform row-range test sends ~90% of blocks down a pure-copy
// path with 4-deep ILP.
//
// R1 lesson: __builtin_nontemporal_store regressed the kernel ~77->95us
// (writes bypass L2 write-combining; plain stores reach the 6.6 TB/s
// streaming-write path the fill kernels use). Plain stores here.

#define HALF   25
#define BATCH  64
#define IMG_H  512
#define IMG_W  512
#define IMG_C  3
#define ELEM_PER_IMG (IMG_H * IMG_W * IMG_C)            // 786432
#define VEC_PER_IMG  (ELEM_PER_IMG / 4)                 // 196608
#define VEC_PER_BLOCK 1024
#define BLOCKS_PER_IMG (VEC_PER_IMG / VEC_PER_BLOCK)    // 192 (exact)
#define N_ELEM ((size_t)BATCH * ELEM_PER_IMG)           // 50,331,648

typedef float f4 __attribute__((ext_vector_type(4)));

__global__ __launch_bounds__(256) void cutout_fused(
    const f4* __restrict__ in,
    f4* __restrict__ out,
    const int* __restrict__ center_h,
    const int* __restrict__ center_w,
    const int* __restrict__ labels,
    float* __restrict__ out_labels)
{
    const int b = blockIdx.y;                   // batch index: block-uniform
    const int chb = center_h[b];                // -> s_load (uniform)
    const int cwb = center_w[b];

    if (blockIdx.x == 0 && b == 0 && threadIdx.x < BATCH) {
        out_labels[threadIdx.x] = (float)labels[threadIdx.x];
    }

    const unsigned vbase_img = blockIdx.x * (unsigned)VEC_PER_BLOCK;  // vec idx within image
    const unsigned gvbase    = (unsigned)b * VEC_PER_IMG + vbase_img;
    const f4* __restrict__ src = in  + gvbase + threadIdx.x;
    f4*       __restrict__ dst = out + gvbase + threadIdx.x;

    // Row range covered by this block (elements [e0, e0+4096) of the image).
    const unsigned e0 = vbase_img * 4u;
    const int r0 = (int)((e0 / 3u) >> 9);
    const int r1 = (int)(((e0 + 4095u) / 3u) >> 9);
    const bool overlap = (r1 >= chb - HALF) & (r0 < chb + HALF);

    // 4 independent 16B loads (MLP depth 4).
    f4 v0 = src[0];
    f4 v1 = src[256];
    f4 v2 = src[512];
    f4 v3 = src[768];

    if (!overlap) {
        dst[0]   = v0;
        dst[256] = v1;
        dst[512] = v2;
        dst[768] = v3;
        return;
    }

    // Mask path (~10% of blocks): per-element box test.
    f4 vv[4] = {v0, v1, v2, v3};

    #pragma unroll
    for (int k = 0; k < 4; ++k) {
        const unsigned vimg = vbase_img + threadIdx.x + (unsigned)k * 256u; // vec idx in image
        const unsigned idx4 = vimg * 4u;          // elem idx in image, < 786432
        const unsigned pi   = idx4 / 3u;          // pixel of elem 0 (magic-mul)
        const unsigned rem  = idx4 - pi * 3u;     // channel of elem 0

        // pixel p -> (h, w) within this image
        const unsigned p0 = pi;
        const unsigned p1 = pi + 1u;              // always < 262144 for valid vecs
        const int w0 = (int)(p0 & (IMG_W - 1));
        const int h0 = (int)(p0 >> 9);
        const int w1 = (int)(p1 & (IMG_W - 1));
        const int h1 = (int)(p1 >> 9);

        const bool m0 = (h0 >= chb - HALF) & (h0 < chb + HALF) &
                        (w0 >= cwb - HALF) & (w0 < cwb + HALF);
        const bool m1 = (h1 >= chb - HALF) & (h1 < chb + HALF) &
                        (w1 >= cwb - HALF) & (w1 < cwb + HALF);

        // e0 -> p0; e1 -> (rem>=2 ? p1 : p0); e2 -> (rem>=1 ? p1 : p0); e3 -> p1
        const bool me0 = m0;
        const bool me1 = (rem >= 2) ? m1 : m0;
        const bool me2 = (rem >= 1) ? m1 : m0;
        const bool me3 = m1;

        f4 v = vv[k];
        if (me0) v[0] = 0.0f;
        if (me1) v[1] = 0.0f;
        if (me2) v[2] = 0.0f;
        if (me3) v[3] = 0.0f;
        dst[k * 256] = v;
    }
}

extern "C" void kernel_launch(void* const* d_in, const int* in_sizes, int n_in,
                              void* d_out, int out_size, void* d_ws, size_t ws_size,
                              hipStream_t stream) {
    const float* images   = (const float*)d_in[0];
    const int*   labels   = (const int*)  d_in[1];
    const int*   center_h = (const int*)  d_in[2];
    const int*   center_w = (const int*)  d_in[3];
    float* out = (float*)d_out;

    dim3 grid(BLOCKS_PER_IMG, BATCH);            // (192, 64) = 12288 blocks
    cutout_fused<<<grid, 256, 0, stream>>>(
        (const f4*)images, (f4*)out,
        center_h, center_w, labels, out + N_ELEM);
}